// Round 9
// baseline (440.953 us; speedup 1.0000x reference)
//
#include <hip/hip_runtime.h>
#include <hip/hip_fp16.h>

#define D 64
#define NBMAX 512      // scan blocks (nodes/256, N<=131072)
#define TILE 64        // nodes per block in tile_layer
#define ASTH 72        // LDS bf16 acc row stride in halves (144B: 16B-aligned, 2-way banks)
#define ACAP 448       // per-wave LDS adjacency buffer (entries)
// R8 lessons: (a) scatter write-amplification theory DEAD -- new coalesced-
// write scatter moved only 17MB yet took 43us (latency-bound at 391 blocks =
// 1.5 blocks/CU). (b) The two-pass CSR build (scatter->bpair, build->adj)
// exists only to sort adjacency by dst -- but since R3 tile_layer's
// lane-owns-row walk needs ONLY row_ptr ranges, not sorted order.
// R9: DIRECT CSR build. edge_hist: per-node counts via 1.6M no-return global
// atomics into 400KB (L2-resident, 2048 blocks). Hierarchical scan (scanA /
// scan_buckets / scanC) -> row_ptr + cursor + dis. edge_scatter: one pass,
// adj[atomicAdd(&cursor[dst])] = src<<6 (2048 blocks, TLP hides atomic
// latency). bpair + bucket_build deleted. Row-internal order becomes
// nondeterministic -- harmless (fp32 accum, tolerance passes with margin).
// tile_layer = proven R6 body, byte-identical.

typedef __attribute__((ext_vector_type(8))) short short8;
typedef __attribute__((ext_vector_type(4))) float float4v;

static __device__ __forceinline__ unsigned short f2bf(float x) {
    unsigned u = __float_as_uint(x);
    u += 0x7FFFu + ((u >> 16) & 1);   // RNE
    return (unsigned short)(u >> 16);
}

__global__ void zero_ints(int* __restrict__ p, int n) {
    int i = blockIdx.x * blockDim.x + threadIdx.x;
    if (i < n) p[i] = 0;
}

// x (fp32) -> xh (fp16), pre-scaled by dis[row]: s = dis[n]*x[n]
__global__ void prescale_x(const float* __restrict__ x, const float* __restrict__ dis,
                           __half* __restrict__ out, int n2) {
    int i = blockIdx.x * blockDim.x + threadIdx.x;
    if (i < n2) {
        int n = i >> 5;                 // 32 half2 per row
        float d = dis[n];
        float2 v = ((const float2*)x)[i];
        ((__half2*)out)[i] = __floats2half2_rn(v.x * d, v.y * d);
    }
}

// Per-node in-degree histogram: fire-and-forget global atomics into 400KB
// (L2-resident). 2048-block grid-stride -> full TLP.
__global__ __launch_bounds__(256) void edge_hist(const int* __restrict__ dst, int E,
                                                 int* __restrict__ nodecnt) {
    int i = blockIdx.x * blockDim.x + threadIdx.x;
    int stride = gridDim.x * blockDim.x;
    for (int e = i; e < E; e += stride) atomicAdd(&nodecnt[dst[e]], 1);
}

// Scan stage A: per-256-node block, exclusive scan of counts (local), block
// total to btot. Also emits dis[n] = rsqrt(cnt+1).
__global__ __launch_bounds__(256) void node_scanA(const int* __restrict__ nodecnt, int N,
                                                  int* __restrict__ row_ptr,
                                                  float* __restrict__ dis,
                                                  int* __restrict__ btot) {
    __shared__ int wsum[4];
    int b = blockIdx.x, t = threadIdx.x;
    int n = (b << 8) + t;
    int val = (n < N) ? nodecnt[n] : 0;
    int lane = t & 63, wv = t >> 6;
    int v = val;
#pragma unroll
    for (int off = 1; off < 64; off <<= 1) {
        int u = __shfl_up(v, off, 64);
        if (lane >= off) v += u;
    }
    if (lane == 63) wsum[wv] = v;
    __syncthreads();
    int wo = 0;
#pragma unroll
    for (int w = 0; w < 4; w++)
        if (w < wv) wo += wsum[w];
    if (n < N) {
        row_ptr[n] = wo + v - val;           // block-local exclusive
        dis[n] = rsqrtf((float)(val + 1));   // +1 self-loop
    }
    if (t == 255) btot[b] = wo + v;          // block total
}

// Scan stage B: exclusive scan of nbb (<512) block totals -> boff, total at
// boff[nbb]. (Same kernel as the old scan_buckets.)
__global__ void scan_buckets(const int* __restrict__ btot, int B, int* __restrict__ boff) {
    __shared__ int s[512];
    int t = threadIdx.x;
    s[t] = (t < B) ? btot[t] : 0;
    __syncthreads();
    for (int off = 1; off < 512; off <<= 1) {
        int v = (t >= off) ? s[t - off] : 0;
        __syncthreads();
        s[t] += v;
        __syncthreads();
    }
    if (t < B) boff[t] = (t == 0) ? 0 : s[t - 1];
    if (t == 0) boff[B] = s[511];
}

// Scan stage C: add block offsets -> final row_ptr; init scatter cursors.
__global__ __launch_bounds__(256) void node_scanC(int* __restrict__ row_ptr,
                                                  int* __restrict__ cursor,
                                                  const int* __restrict__ boff,
                                                  int N, int nbb) {
    int n = blockIdx.x * blockDim.x + threadIdx.x;
    if (n < N) {
        int r = row_ptr[n] + boff[n >> 8];
        row_ptr[n] = r;
        cursor[n] = r;
    }
    if (n == 0) row_ptr[N] = boff[nbb];
}

// Direct CSR scatter: adj[pos] = (src<<6)|(dst&63) at pos = cursor[dst]++.
// 1.6M atomic-returns into the hot 400KB cursor; 2048-block TLP hides the
// round-trip. Row-internal order nondeterministic (harmless).
__global__ __launch_bounds__(256) void edge_scatter(const int* __restrict__ src,
                                                    const int* __restrict__ dst, int E,
                                                    int* __restrict__ cursor,
                                                    int* __restrict__ adj) {
    int i = blockIdx.x * blockDim.x + threadIdx.x;
    int stride = gridDim.x * blockDim.x;
    for (int e = i; e < E; e += stride) {
        int d = dst[e];
        int pos = atomicAdd(&cursor[d], 1);
        adj[pos] = (src[e] << 6) | (d & 63);
    }
}

// Tile GCN layer on pre-scaled storage s[n] = dis[n]*h[n]:  (R6 body, proven)
//   y[n] = dis[n] * ( sum_a s[a] + s[n] );  o = relu(y @ W + b); store (*dis if scale_out)
// Block = 64-node tile, 4 waves x 16 rows. Lane = (row = lane>>2, c = lane&3).
// Contiguous-quad gather: lane c owns row bytes [c*16,+16) and [64+c*16,+16);
// each quad load = one fully-used 64B line. Per-lane fp32 register
// accumulation, no LDS atomics, no divergence. Epilogue: *dis, bf16 pack,
// two 16B LDS writes, wave-local waitcnt, per-wave MFMA.
template <int NB>
static __device__ __forceinline__ void tile_layer_body(const __half* __restrict__ in,
                                                       const int* __restrict__ row_ptr,
                                                       const int* __restrict__ adj,
                                                       const float* __restrict__ dis,
                                                       const float* __restrict__ Wg,
                                                       const float* __restrict__ bias,
                                                       __half* __restrict__ out,
                                                       int N, int scale_out) {
    __shared__ __align__(16) unsigned short accb[TILE * ASTH];  // 9216 B bf16 acc
    __shared__ int adjbuf[4][ACAP];                             // 7168 B wave-private

    int t = threadIdx.x;
    int lane = t & 63;
    int w = t >> 6;
    int row = lane >> 2;                    // wave-local row 0..15
    int c = lane & 3;                       // quad slot
    int col = lane & 15, quad = lane >> 4;  // epilogue MFMA coords

    int t0 = blockIdx.x * TILE;
    int wbase = t0 + w * 16;
    int node = wbase + row;

    // per-lane CSR range (empty for tail rows)
    int e0r = 0, e1r = 0;
    if (node < N) { e0r = row_ptr[node]; e1r = row_ptr[node + 1]; }

    const char* inb = (const char*)in;
    int* adjw = adjbuf[w];
    unsigned c16 = (unsigned)c * 16u;       // byte offset within each 64B half-row

    float a[16];                            // a[0..7]=ch[8c..8c+8), a[8..15]=ch[32+8c..)
#pragma unroll
    for (int j = 0; j < 16; j++) a[j] = 0.f;

#define ADD16(xa, ya)                                                   \
    {                                                                   \
        const __half2* h0 = (const __half2*)&(xa);                      \
        const __half2* h1 = (const __half2*)&(ya);                      \
        _Pragma("unroll")                                               \
        for (int j = 0; j < 4; j++) {                                   \
            float2 f = __half22float2(h0[j]);                           \
            a[2 * j] += f.x; a[2 * j + 1] += f.y;                       \
        }                                                               \
        _Pragma("unroll")                                               \
        for (int j = 0; j < 4; j++) {                                   \
            float2 f = __half22float2(h1[j]);                           \
            a[8 + 2 * j] += f.x; a[8 + 2 * j + 1] += f.y;               \
        }                                                               \
    }

    if (node < N) {
        unsigned rb = (unsigned)node * 128u + c16;
        int4 xa = *(const int4*)(inb + rb);
        int4 xb = *(const int4*)(inb + rb + 64);
        ADD16(xa, xb)
    }

    // ---- edge sweep: wave's contiguous CSR range, staged in ACAP chunks ----
    int wn0 = min(wbase, N);
    int wn1 = min(wbase + 16, N);
    int eb_w = row_ptr[wn0];
    int ee_w = row_ptr[wn1];

    for (int base = eb_w; base < ee_w; base += ACAP) {
        int clen = min(ACAP, ee_w - base);
        // cooperative wave-copy of adj slice (coalesced dwords); wave-private.
        for (int i = lane; i < clen; i += 64) adjw[i] = adj[base + i];
        __builtin_amdgcn_s_waitcnt(0);   // drain lds writes + vm before reads

        int ls = max(e0r - base, 0);
        int le = min(e1r - base, clen);
        int cnt = max(le - ls, 0);
        int kmax = cnt;
#pragma unroll
        for (int off = 32; off >= 1; off >>= 1) {
            int o = __shfl_xor(kmax, off, 64);
            kmax = max(kmax, o);
        }
        int sidx = min(ls, clen - 1);    // safe clamped index for short lanes

        for (int k = 0; k < kmax; k += NB) {
            bool ok[NB];
            unsigned ro[NB];
            int4 xa[NB], xb[NB];
#pragma unroll
            for (int u = 0; u < NB; u++) {
                int idx = ls + k + u;
                ok[u] = idx < le;
                int pk = adjw[ok[u] ? idx : sidx];
                ro[u] = (unsigned)(pk >> 6) * 128u + c16;
            }
#pragma unroll
            for (int u = 0; u < NB; u++) {
                xa[u] = *(const int4*)(inb + ro[u]);        // quad: one 64B line
                xb[u] = *(const int4*)(inb + ro[u] + 64);   // quad: one 64B line
            }
#pragma unroll
            for (int u = 0; u < NB; u++)
                if (ok[u]) ADD16(xa[u], xb[u])
        }
    }
#undef ADD16

    // scale by dis(own row), convert to bf16, two 16B LDS writes
    float dA = (node < N) ? dis[node] : 0.f;
    unsigned short* ab = &accb[(w * 16 + row) * ASTH];
    unsigned pk[8];
#pragma unroll
    for (int j = 0; j < 8; j++)
        pk[j] = (unsigned)f2bf(a[2 * j] * dA) | ((unsigned)f2bf(a[2 * j + 1] * dA) << 16);
    *(int4*)(ab + 8 * c) = make_int4((int)pk[0], (int)pk[1], (int)pk[2], (int)pk[3]);
    *(int4*)(ab + 32 + 8 * c) = make_int4((int)pk[4], (int)pk[5], (int)pk[6], (int)pk[7]);
    __builtin_amdgcn_s_waitcnt(0);   // wave-local: acc rows read only by this wave

    // ---- MFMA epilogue: per wave, rows w*16 .. w*16+15 ----
    // A frags: row m = col, k = 32s + quad*8 + j (bf16 direct from LDS)
    const unsigned short* arp = &accb[(w * 16 + col) * ASTH + quad * 8];
    short8 Af0 = *(const short8*)arp;
    short8 Af1 = *(const short8*)(arp + 32);

    float dnv[4];
#pragma unroll
    for (int r = 0; r < 4; r++) {
        int onode = t0 + w * 16 + quad * 4 + r;
        dnv[r] = (onode < N) ? (scale_out ? dis[onode] : 1.f) : 0.f;
    }

    // B frags per output quadrant cc: B[k=32s+quad*8+j][d=16cc+col]
#pragma unroll
    for (int cc = 0; cc < 4; cc++) {
        short8 B0, B1;
#pragma unroll
        for (int j = 0; j < 8; j++) {
            B0[j] = (short)f2bf(Wg[(quad * 8 + j) * D + 16 * cc + col]);
            B1[j] = (short)f2bf(Wg[(32 + quad * 8 + j) * D + 16 * cc + col]);
        }
        float4v z = {0.f, 0.f, 0.f, 0.f};
        float4v v = __builtin_amdgcn_mfma_f32_16x16x32_bf16(Af0, B0, z, 0, 0, 0);
        v = __builtin_amdgcn_mfma_f32_16x16x32_bf16(Af1, B1, v, 0, 0, 0);
        float bc = bias[16 * cc + col];
        // C layout: col = lane&15 (dim 16cc+col), row = quad*4 + r (node)
#pragma unroll
        for (int r = 0; r < 4; r++) {
            int onode = t0 + w * 16 + quad * 4 + r;
            if (onode < N) {
                float vv = fmaxf(v[r] + bc, 0.f) * dnv[r];
                out[(long)onode * D + 16 * cc + col] = __float2half(vv);
            }
        }
    }
}

// Single variant: batch-4 sweep, natural register allocation.
__global__ __launch_bounds__(256) void tile_layer(const __half* __restrict__ in,
                                                  const int* __restrict__ row_ptr,
                                                  const int* __restrict__ adj,
                                                  const float* __restrict__ dis,
                                                  const float* __restrict__ Wg,
                                                  const float* __restrict__ bias,
                                                  __half* __restrict__ out,
                                                  int N, int scale_out) {
    tile_layer_body<4>(in, row_ptr, adj, dis, Wg, bias, out, N, scale_out);
}

// Pool phase 1: grid-chunked over sorted nodes; per-wave run accumulation,
// one atomicAdd per (graph-run, lane) per wave.
__global__ __launch_bounds__(256) void pool_partial(const __half* __restrict__ h,
                                                    const int* __restrict__ batch, int N,
                                                    int chunk, float* __restrict__ pooled) {
    int lane = threadIdx.x & 63;
    int wv = threadIdx.x >> 6;
    int c0 = blockIdx.x * chunk;
    int c1 = min(c0 + chunk, N);
    int g_cur = -1;
    float acc = 0.f;
    for (int n = c0 + wv; n < c1; n += 4) {
        int g = batch[n];
        if (g != g_cur) {
            if (g_cur >= 0) atomicAdd(&pooled[g_cur * D + lane], acc);
            g_cur = g;
            acc = 0.f;
        }
        acc += __half2float(h[n * D + lane]);
    }
    if (g_cur >= 0) atomicAdd(&pooled[g_cur * D + lane], acc);
}

// Pool phase 2: one wave per graph, dot with lin_w.
__global__ void pool_linear(const float* __restrict__ pooled,
                            const float* __restrict__ lin_w,
                            const float* __restrict__ lin_b,
                            float* __restrict__ out, int G) {
    int lane = threadIdx.x & 63;
    int g = blockIdx.x * (blockDim.x >> 6) + (threadIdx.x >> 6);
    if (g >= G) return;
    float t = pooled[g * D + lane] * lin_w[lane];
#pragma unroll
    for (int off = 32; off >= 1; off >>= 1) t += __shfl_down(t, off, 64);
    if (lane == 0) out[g] = t + lin_b[0];
}

extern "C" void kernel_launch(void* const* d_in, const int* in_sizes, int n_in,
                              void* d_out, int out_size, void* d_ws, size_t ws_size,
                              hipStream_t stream) {
    const float* x      = (const float*)d_in[0];
    const int*   edges  = (const int*)d_in[1];
    const int*   batch  = (const int*)d_in[2];
    const float* W1     = (const float*)d_in[3];
    const float* b1     = (const float*)d_in[4];
    const float* W2     = (const float*)d_in[5];
    const float* b2     = (const float*)d_in[6];
    const float* W3     = (const float*)d_in[7];
    const float* b3     = (const float*)d_in[8];
    const float* lin_w  = (const float*)d_in[9];
    const float* lin_b  = (const float*)d_in[10];
    float* out = (float*)d_out;

    const int N = in_sizes[2];        // 100000
    const int E = in_sizes[1] / 2;    // 1600000
    const int G = out_size;           // 64 graphs
    const int nbb = (N + 255) >> 8;   // 391 scan blocks of 256 nodes

    const int* e_src = edges;         // edge_index[0]
    const int* e_dst = edges + E;     // edge_index[1]

    // workspace layout (4B-element offsets, 64-elem aligned)
    auto al = [](long v) { return (v + 63) & ~63L; };
    long o_nodecnt = 0;                          // N (zeroed)
    long o_pooled  = al(o_nodecnt + N);          // G*D (zeroed, contiguous-ish)
    long o_btot    = al(o_pooled + (long)G * D); // NBMAX
    long o_boff    = al(o_btot + NBMAX);         // NBMAX+1
    long o_rowptr  = al(o_boff + NBMAX + 1);     // N+1
    long o_cursor  = al(o_rowptr + N + 1);       // N
    long o_dis     = al(o_cursor + N);           // N
    long o_adjs    = al(o_dis + N);              // E
    long o_xh      = al(o_adjs + E);             // N*D halves (N*D/2 ints)
    long o_hA      = al(o_xh + (long)N * D / 2); // N*D halves
    long o_hB      = al(o_hA + (long)N * D / 2); // N*D halves

    int*    nodecnt = (int*)d_ws + o_nodecnt;
    float*  pooled  = (float*)d_ws + o_pooled;
    int*    btot    = (int*)d_ws + o_btot;
    int*    boff    = (int*)d_ws + o_boff;
    int*    row_ptr = (int*)d_ws + o_rowptr;
    int*    cursor  = (int*)d_ws + o_cursor;
    float*  dis     = (float*)d_ws + o_dis;
    int*    adj     = (int*)d_ws + o_adjs;
    __half* xh      = (__half*)((float*)d_ws + o_xh);
    __half* hA      = (__half*)((float*)d_ws + o_hA);
    __half* hB      = (__half*)((float*)d_ws + o_hB);

    // zero nodecnt + pooled (contiguous span)
    int nz = (int)(o_pooled + (long)G * D);
    zero_ints<<<(nz + 255) / 256, 256, 0, stream>>>((int*)d_ws, nz);

    // direct CSR build: hist -> scanA -> scanB -> scanC -> scatter
    edge_hist<<<2048, 256, 0, stream>>>(e_dst, E, nodecnt);
    node_scanA<<<nbb, 256, 0, stream>>>(nodecnt, N, row_ptr, dis, btot);
    scan_buckets<<<1, 512, 0, stream>>>(btot, nbb, boff);
    node_scanC<<<(N + 255) / 256, 256, 0, stream>>>(row_ptr, cursor, boff, N, nbb);
    edge_scatter<<<2048, 256, 0, stream>>>(e_src, e_dst, E, cursor, adj);

    // pre-scaled fp16 convert of x (dis ready after scanA)
    int n2 = N * D / 2;
    prescale_x<<<(n2 + 255) / 256, 256, 0, stream>>>(x, dis, xh, n2);

    // fused GCN layers: xh -> hB -> hA -> hB
    // layers 1,2 store dis-pre-scaled output; layer 3 stores plain relu for pooling
    const int tl_blocks = (N + TILE - 1) / TILE;
    tile_layer<<<tl_blocks, 256, 0, stream>>>(xh, row_ptr, adj, dis, W1, b1, hB, N, 1);
    tile_layer<<<tl_blocks, 256, 0, stream>>>(hB, row_ptr, adj, dis, W2, b2, hA, N, 1);
    tile_layer<<<tl_blocks, 256, 0, stream>>>(hA, row_ptr, adj, dis, W3, b3, hB, N, 0);

    // pool + final linear
    const int pool_blocks = 512;
    const int chunk = (N + pool_blocks - 1) / pool_blocks;
    pool_partial<<<pool_blocks, 256, 0, stream>>>(hB, batch, N, chunk, pooled);
    pool_linear<<<(G + 3) / 4, 256, 0, stream>>>(pooled, lin_w, lin_b, out, G);
}

// Round 10
// 360.277 us; speedup vs baseline: 1.2239x; 1.2239x over previous
//
#include <hip/hip_runtime.h>
#include <hip/hip_fp16.h>

#define D 64
#define NBMAX 512      // max buckets / scan blocks (N<=131072)
#define BCAP 5120      // per-bucket capacity
#define TILE 64        // nodes per block in tile_layer
#define ASTH 72        // LDS bf16 acc row stride in halves (144B: 16B-aligned, 2-way banks)
#define ACAP 448       // per-wave LDS adjacency buffer (entries)
// R9 lessons: (a) direct edge_scatter WRITE amplification 16x (106MB for
// 6.4MB adj; each random 4B store = a 64B partial-line writeback; a node's
// edges arrive from ~16 blocks/XCDs over the whole kernel -> no merging).
// BUCKETING EXISTS FOR WRITE CLUSTERING, not sorting. (b) old bucket_build's
// wall was ~9K LDS atomics/block through the single per-CU LDS pipe (R2
// lesson recurs).
// R10: keep the bucket pass (write locality), kill the LDS-atomic build:
//   bucket_scatter (R0 form) += fire-and-forget global nodecnt atomics
//     (no-return -> no latency chain) -> per-node counts in the same pass.
//   row_ptr/cursor/dis via R9 hierarchical scans (~6us, measured fast).
//   build_scatter: bpair -> adj with GLOBAL cursor atomics (L2-distributed,
//     not LDS pipe), 4 blocks/bucket -> node's writes confined to <=4 blocks
//     in one 17KB region (merging kept, parallelism 4x).
//   bucket_build + edge_hist deleted. tile_layer = proven R6 body.

typedef __attribute__((ext_vector_type(8))) short short8;
typedef __attribute__((ext_vector_type(4))) float float4v;

static __device__ __forceinline__ unsigned short f2bf(float x) {
    unsigned u = __float_as_uint(x);
    u += 0x7FFFu + ((u >> 16) & 1);   // RNE
    return (unsigned short)(u >> 16);
}

__global__ void zero_ints(int* __restrict__ p, int n) {
    int i = blockIdx.x * blockDim.x + threadIdx.x;
    if (i < n) p[i] = 0;
}

// x (fp32) -> xh (fp16), pre-scaled by dis[row]: s = dis[n]*x[n]
__global__ void prescale_x(const float* __restrict__ x, const float* __restrict__ dis,
                           __half* __restrict__ out, int n2) {
    int i = blockIdx.x * blockDim.x + threadIdx.x;
    if (i < n2) {
        int n = i >> 5;                 // 32 half2 per row
        float d = dis[n];
        float2 v = ((const float2*)x)[i];
        ((__half2*)out)[i] = __floats2half2_rn(v.x * d, v.y * d);
    }
}

// Bin edges into buckets of 256 consecutive dst nodes. Entry packed to 4B:
// (src << 8) | (dst & 255)   (src < 2^24). Also accumulates per-node
// in-degree via fire-and-forget global atomics (no return -> issue-rate only).
__global__ __launch_bounds__(256) void bucket_scatter(const int* __restrict__ src,
                                                      const int* __restrict__ dst, int E,
                                                      int nb, int* __restrict__ gcursor,
                                                      unsigned* __restrict__ bpair,
                                                      int* __restrict__ nodecnt) {
    __shared__ int lhist[NBMAX];
    __shared__ int lbase[NBMAX];
    int t = threadIdx.x;
    for (int i = t; i < nb; i += 256) lhist[i] = 0;
    __syncthreads();
    int e0 = blockIdx.x * 4096, e1 = min(e0 + 4096, E);
    for (int e = e0 + t; e < e1; e += 256) {
        int d = dst[e];
        atomicAdd(&lhist[d >> 8], 1);
        atomicAdd(&nodecnt[d], 1);       // fire-and-forget, L2-resident 400KB
    }
    __syncthreads();
    for (int i = t; i < nb; i += 256) {
        int c = lhist[i];
        lbase[i] = c ? atomicAdd(&gcursor[i], c) : 0;
        lhist[i] = 0;
    }
    __syncthreads();
    for (int e = e0 + t; e < e1; e += 256) {
        int d = dst[e];
        int b = d >> 8;
        int r = lbase[b] + atomicAdd(&lhist[b], 1);
        if (r < BCAP)
            bpair[(long)b * BCAP + r] = ((unsigned)src[e] << 8) | (unsigned)(d & 255);
    }
}

// Scan stage A: per-256-node block, exclusive scan of counts (local), block
// total to btot. Also emits dis[n] = rsqrt(cnt+1).
__global__ __launch_bounds__(256) void node_scanA(const int* __restrict__ nodecnt, int N,
                                                  int* __restrict__ row_ptr,
                                                  float* __restrict__ dis,
                                                  int* __restrict__ btot) {
    __shared__ int wsum[4];
    int b = blockIdx.x, t = threadIdx.x;
    int n = (b << 8) + t;
    int val = (n < N) ? nodecnt[n] : 0;
    int lane = t & 63, wv = t >> 6;
    int v = val;
#pragma unroll
    for (int off = 1; off < 64; off <<= 1) {
        int u = __shfl_up(v, off, 64);
        if (lane >= off) v += u;
    }
    if (lane == 63) wsum[wv] = v;
    __syncthreads();
    int wo = 0;
#pragma unroll
    for (int w = 0; w < 4; w++)
        if (w < wv) wo += wsum[w];
    if (n < N) {
        row_ptr[n] = wo + v - val;           // block-local exclusive
        dis[n] = rsqrtf((float)(val + 1));   // +1 self-loop
    }
    if (t == 255) btot[b] = wo + v;          // block total
}

// Scan stage B: exclusive scan of nbb (<512) block totals -> boff, total at boff[nbb].
__global__ void scan_buckets(const int* __restrict__ btot, int B, int* __restrict__ boff) {
    __shared__ int s[512];
    int t = threadIdx.x;
    s[t] = (t < B) ? btot[t] : 0;
    __syncthreads();
    for (int off = 1; off < 512; off <<= 1) {
        int v = (t >= off) ? s[t - off] : 0;
        __syncthreads();
        s[t] += v;
        __syncthreads();
    }
    if (t < B) boff[t] = (t == 0) ? 0 : s[t - 1];
    if (t == 0) boff[B] = s[511];
}

// Scan stage C: add block offsets -> final row_ptr; init scatter cursors.
__global__ __launch_bounds__(256) void node_scanC(int* __restrict__ row_ptr,
                                                  int* __restrict__ cursor,
                                                  const int* __restrict__ boff,
                                                  int N, int nbb) {
    int n = blockIdx.x * blockDim.x + threadIdx.x;
    if (n < N) {
        int r = row_ptr[n] + boff[n >> 8];
        row_ptr[n] = r;
        cursor[n] = r;
    }
    if (n == 0) row_ptr[N] = boff[nbb];
}

// bpair -> adj. 4 blocks per bucket (block = (bucket, quarter)); pos from
// GLOBAL cursor atomics (L2-distributed; not the per-CU LDS pipe). A node's
// writes are confined to <=4 blocks within one ~17KB bucket region -> line
// merging preserved (the R9 amplification came from all-XCD scatter).
__global__ __launch_bounds__(256) void build_scatter(const unsigned* __restrict__ bpair,
                                                     int nb, int N,
                                                     const int* __restrict__ gcursor,
                                                     int* __restrict__ cursor,
                                                     int* __restrict__ adj) {
    int b = blockIdx.x >> 2, q = blockIdx.x & 3;
    int cnt = min(gcursor[b], BCAP);
    int i0 = (cnt * q) >> 2;
    int i1 = (cnt * (q + 1)) >> 2;
    const unsigned* bp = bpair + (long)b * BCAP;
    for (int i = i0 + (int)threadIdx.x; i < i1; i += 256) {
        unsigned p = bp[i];
        int node = (b << 8) + (int)(p & 255u);
        int pos = atomicAdd(&cursor[node], 1);
        adj[pos] = (int)((p >> 8) << 6) | (int)(p & 63u);
    }
}

// Tile GCN layer on pre-scaled storage s[n] = dis[n]*h[n]:  (R6 body, proven)
//   y[n] = dis[n] * ( sum_a s[a] + s[n] );  o = relu(y @ W + b); store (*dis if scale_out)
// Block = 64-node tile, 4 waves x 16 rows. Lane = (row = lane>>2, c = lane&3).
// Contiguous-quad gather: lane c owns row bytes [c*16,+16) and [64+c*16,+16);
// each quad load = one fully-used 64B line. Per-lane fp32 register
// accumulation, no LDS atomics, no divergence. Epilogue: *dis, bf16 pack,
// two 16B LDS writes, wave-local waitcnt, per-wave MFMA.
template <int NB>
static __device__ __forceinline__ void tile_layer_body(const __half* __restrict__ in,
                                                       const int* __restrict__ row_ptr,
                                                       const int* __restrict__ adj,
                                                       const float* __restrict__ dis,
                                                       const float* __restrict__ Wg,
                                                       const float* __restrict__ bias,
                                                       __half* __restrict__ out,
                                                       int N, int scale_out) {
    __shared__ __align__(16) unsigned short accb[TILE * ASTH];  // 9216 B bf16 acc
    __shared__ int adjbuf[4][ACAP];                             // 7168 B wave-private

    int t = threadIdx.x;
    int lane = t & 63;
    int w = t >> 6;
    int row = lane >> 2;                    // wave-local row 0..15
    int c = lane & 3;                       // quad slot
    int col = lane & 15, quad = lane >> 4;  // epilogue MFMA coords

    int t0 = blockIdx.x * TILE;
    int wbase = t0 + w * 16;
    int node = wbase + row;

    // per-lane CSR range (empty for tail rows)
    int e0r = 0, e1r = 0;
    if (node < N) { e0r = row_ptr[node]; e1r = row_ptr[node + 1]; }

    const char* inb = (const char*)in;
    int* adjw = adjbuf[w];
    unsigned c16 = (unsigned)c * 16u;       // byte offset within each 64B half-row

    float a[16];                            // a[0..7]=ch[8c..8c+8), a[8..15]=ch[32+8c..)
#pragma unroll
    for (int j = 0; j < 16; j++) a[j] = 0.f;

#define ADD16(xa, ya)                                                   \
    {                                                                   \
        const __half2* h0 = (const __half2*)&(xa);                      \
        const __half2* h1 = (const __half2*)&(ya);                      \
        _Pragma("unroll")                                               \
        for (int j = 0; j < 4; j++) {                                   \
            float2 f = __half22float2(h0[j]);                           \
            a[2 * j] += f.x; a[2 * j + 1] += f.y;                       \
        }                                                               \
        _Pragma("unroll")                                               \
        for (int j = 0; j < 4; j++) {                                   \
            float2 f = __half22float2(h1[j]);                           \
            a[8 + 2 * j] += f.x; a[8 + 2 * j + 1] += f.y;               \
        }                                                               \
    }

    if (node < N) {
        unsigned rb = (unsigned)node * 128u + c16;
        int4 xa = *(const int4*)(inb + rb);
        int4 xb = *(const int4*)(inb + rb + 64);
        ADD16(xa, xb)
    }

    // ---- edge sweep: wave's contiguous CSR range, staged in ACAP chunks ----
    int wn0 = min(wbase, N);
    int wn1 = min(wbase + 16, N);
    int eb_w = row_ptr[wn0];
    int ee_w = row_ptr[wn1];

    for (int base = eb_w; base < ee_w; base += ACAP) {
        int clen = min(ACAP, ee_w - base);
        // cooperative wave-copy of adj slice (coalesced dwords); wave-private.
        for (int i = lane; i < clen; i += 64) adjw[i] = adj[base + i];
        __builtin_amdgcn_s_waitcnt(0);   // drain lds writes + vm before reads

        int ls = max(e0r - base, 0);
        int le = min(e1r - base, clen);
        int cnt = max(le - ls, 0);
        int kmax = cnt;
#pragma unroll
        for (int off = 32; off >= 1; off >>= 1) {
            int o = __shfl_xor(kmax, off, 64);
            kmax = max(kmax, o);
        }
        int sidx = min(ls, clen - 1);    // safe clamped index for short lanes

        for (int k = 0; k < kmax; k += NB) {
            bool ok[NB];
            unsigned ro[NB];
            int4 xa[NB], xb[NB];
#pragma unroll
            for (int u = 0; u < NB; u++) {
                int idx = ls + k + u;
                ok[u] = idx < le;
                int pk = adjw[ok[u] ? idx : sidx];
                ro[u] = (unsigned)(pk >> 6) * 128u + c16;
            }
#pragma unroll
            for (int u = 0; u < NB; u++) {
                xa[u] = *(const int4*)(inb + ro[u]);        // quad: one 64B line
                xb[u] = *(const int4*)(inb + ro[u] + 64);   // quad: one 64B line
            }
#pragma unroll
            for (int u = 0; u < NB; u++)
                if (ok[u]) ADD16(xa[u], xb[u])
        }
    }
#undef ADD16

    // scale by dis(own row), convert to bf16, two 16B LDS writes
    float dA = (node < N) ? dis[node] : 0.f;
    unsigned short* ab = &accb[(w * 16 + row) * ASTH];
    unsigned pk[8];
#pragma unroll
    for (int j = 0; j < 8; j++)
        pk[j] = (unsigned)f2bf(a[2 * j] * dA) | ((unsigned)f2bf(a[2 * j + 1] * dA) << 16);
    *(int4*)(ab + 8 * c) = make_int4((int)pk[0], (int)pk[1], (int)pk[2], (int)pk[3]);
    *(int4*)(ab + 32 + 8 * c) = make_int4((int)pk[4], (int)pk[5], (int)pk[6], (int)pk[7]);
    __builtin_amdgcn_s_waitcnt(0);   // wave-local: acc rows read only by this wave

    // ---- MFMA epilogue: per wave, rows w*16 .. w*16+15 ----
    // A frags: row m = col, k = 32s + quad*8 + j (bf16 direct from LDS)
    const unsigned short* arp = &accb[(w * 16 + col) * ASTH + quad * 8];
    short8 Af0 = *(const short8*)arp;
    short8 Af1 = *(const short8*)(arp + 32);

    float dnv[4];
#pragma unroll
    for (int r = 0; r < 4; r++) {
        int onode = t0 + w * 16 + quad * 4 + r;
        dnv[r] = (onode < N) ? (scale_out ? dis[onode] : 1.f) : 0.f;
    }

    // B frags per output quadrant cc: B[k=32s+quad*8+j][d=16cc+col]
#pragma unroll
    for (int cc = 0; cc < 4; cc++) {
        short8 B0, B1;
#pragma unroll
        for (int j = 0; j < 8; j++) {
            B0[j] = (short)f2bf(Wg[(quad * 8 + j) * D + 16 * cc + col]);
            B1[j] = (short)f2bf(Wg[(32 + quad * 8 + j) * D + 16 * cc + col]);
        }
        float4v z = {0.f, 0.f, 0.f, 0.f};
        float4v v = __builtin_amdgcn_mfma_f32_16x16x32_bf16(Af0, B0, z, 0, 0, 0);
        v = __builtin_amdgcn_mfma_f32_16x16x32_bf16(Af1, B1, v, 0, 0, 0);
        float bc = bias[16 * cc + col];
        // C layout: col = lane&15 (dim 16cc+col), row = quad*4 + r (node)
#pragma unroll
        for (int r = 0; r < 4; r++) {
            int onode = t0 + w * 16 + quad * 4 + r;
            if (onode < N) {
                float vv = fmaxf(v[r] + bc, 0.f) * dnv[r];
                out[(long)onode * D + 16 * cc + col] = __float2half(vv);
            }
        }
    }
}

// Single variant: batch-4 sweep, natural register allocation.
__global__ __launch_bounds__(256) void tile_layer(const __half* __restrict__ in,
                                                  const int* __restrict__ row_ptr,
                                                  const int* __restrict__ adj,
                                                  const float* __restrict__ dis,
                                                  const float* __restrict__ Wg,
                                                  const float* __restrict__ bias,
                                                  __half* __restrict__ out,
                                                  int N, int scale_out) {
    tile_layer_body<4>(in, row_ptr, adj, dis, Wg, bias, out, N, scale_out);
}

// Pool phase 1: grid-chunked over sorted nodes; per-wave run accumulation,
// one atomicAdd per (graph-run, lane) per wave.
__global__ __launch_bounds__(256) void pool_partial(const __half* __restrict__ h,
                                                    const int* __restrict__ batch, int N,
                                                    int chunk, float* __restrict__ pooled) {
    int lane = threadIdx.x & 63;
    int wv = threadIdx.x >> 6;
    int c0 = blockIdx.x * chunk;
    int c1 = min(c0 + chunk, N);
    int g_cur = -1;
    float acc = 0.f;
    for (int n = c0 + wv; n < c1; n += 4) {
        int g = batch[n];
        if (g != g_cur) {
            if (g_cur >= 0) atomicAdd(&pooled[g_cur * D + lane], acc);
            g_cur = g;
            acc = 0.f;
        }
        acc += __half2float(h[n * D + lane]);
    }
    if (g_cur >= 0) atomicAdd(&pooled[g_cur * D + lane], acc);
}

// Pool phase 2: one wave per graph, dot with lin_w.
__global__ void pool_linear(const float* __restrict__ pooled,
                            const float* __restrict__ lin_w,
                            const float* __restrict__ lin_b,
                            float* __restrict__ out, int G) {
    int lane = threadIdx.x & 63;
    int g = blockIdx.x * (blockDim.x >> 6) + (threadIdx.x >> 6);
    if (g >= G) return;
    float t = pooled[g * D + lane] * lin_w[lane];
#pragma unroll
    for (int off = 32; off >= 1; off >>= 1) t += __shfl_down(t, off, 64);
    if (lane == 0) out[g] = t + lin_b[0];
}

extern "C" void kernel_launch(void* const* d_in, const int* in_sizes, int n_in,
                              void* d_out, int out_size, void* d_ws, size_t ws_size,
                              hipStream_t stream) {
    const float* x      = (const float*)d_in[0];
    const int*   edges  = (const int*)d_in[1];
    const int*   batch  = (const int*)d_in[2];
    const float* W1     = (const float*)d_in[3];
    const float* b1     = (const float*)d_in[4];
    const float* W2     = (const float*)d_in[5];
    const float* b2     = (const float*)d_in[6];
    const float* W3     = (const float*)d_in[7];
    const float* b3     = (const float*)d_in[8];
    const float* lin_w  = (const float*)d_in[9];
    const float* lin_b  = (const float*)d_in[10];
    float* out = (float*)d_out;

    const int N = in_sizes[2];        // 100000
    const int E = in_sizes[1] / 2;    // 1600000
    const int G = out_size;           // 64 graphs
    const int nb = (N + 255) >> 8;    // 391 buckets of 256 nodes

    const int* e_src = edges;         // edge_index[0]
    const int* e_dst = edges + E;     // edge_index[1]

    // workspace layout (4B-element offsets, 64-elem aligned)
    auto al = [](long v) { return (v + 63) & ~63L; };
    long o_gcur    = 0;                           // NBMAX (zeroed)
    long o_nodecnt = al(o_gcur + NBMAX);          // N (zeroed)
    long o_pooled  = al(o_nodecnt + N);           // G*D (zeroed)
    long o_btot    = al(o_pooled + (long)G * D);  // NBMAX
    long o_boff    = al(o_btot + NBMAX);          // NBMAX+1
    long o_rowptr  = al(o_boff + NBMAX + 1);      // N+1
    long o_cursor  = al(o_rowptr + N + 1);        // N
    long o_dis     = al(o_cursor + N);            // N
    long o_adjs    = al(o_dis + N);               // E
    long o_xh      = al(o_adjs + E);              // N*D halves
    long o_hA      = al(o_xh + (long)N * D / 2);  // fp32-sized slot (bpair aliases)
    long o_hB      = o_hA + (long)N * D;          // fp32-sized slot

    int*    gcursor = (int*)d_ws + o_gcur;
    int*    nodecnt = (int*)d_ws + o_nodecnt;
    float*  pooled  = (float*)d_ws + o_pooled;
    int*    btot    = (int*)d_ws + o_btot;
    int*    boff    = (int*)d_ws + o_boff;
    int*    row_ptr = (int*)d_ws + o_rowptr;
    int*    cursor  = (int*)d_ws + o_cursor;
    float*  dis     = (float*)d_ws + o_dis;
    int*    adj     = (int*)d_ws + o_adjs;
    __half* xh      = (__half*)((float*)d_ws + o_xh);
    __half* hA      = (__half*)((float*)d_ws + o_hA);
    __half* hB      = (__half*)((float*)d_ws + o_hB);
    // bpair (nb*BCAP uints = 8 MB) aliases hA slot (25.6MB): dead before
    // layer 2 writes hA.
    unsigned* bpair = (unsigned*)hA;

    // zero gcursor + nodecnt + pooled (one contiguous span)
    int nz = (int)(o_pooled + (long)G * D);
    zero_ints<<<(nz + 255) / 256, 256, 0, stream>>>((int*)d_ws, nz);

    // CSR build: scatter (buckets + per-node counts) -> scans -> build_scatter
    bucket_scatter<<<(E + 4095) / 4096, 256, 0, stream>>>(e_src, e_dst, E, nb,
                                                          gcursor, bpair, nodecnt);
    node_scanA<<<nb, 256, 0, stream>>>(nodecnt, N, row_ptr, dis, btot);
    scan_buckets<<<1, 512, 0, stream>>>(btot, nb, boff);
    node_scanC<<<(N + 255) / 256, 256, 0, stream>>>(row_ptr, cursor, boff, N, nb);
    build_scatter<<<nb * 4, 256, 0, stream>>>(bpair, nb, N, gcursor, cursor, adj);

    // pre-scaled fp16 convert of x (dis ready after scanA)
    int n2 = N * D / 2;
    prescale_x<<<(n2 + 255) / 256, 256, 0, stream>>>(x, dis, xh, n2);

    // fused GCN layers: xh -> hB -> hA -> hB
    // layers 1,2 store dis-pre-scaled output; layer 3 stores plain relu for pooling
    const int tl_blocks = (N + TILE - 1) / TILE;
    tile_layer<<<tl_blocks, 256, 0, stream>>>(xh, row_ptr, adj, dis, W1, b1, hB, N, 1);
    tile_layer<<<tl_blocks, 256, 0, stream>>>(hB, row_ptr, adj, dis, W2, b2, hA, N, 1);
    tile_layer<<<tl_blocks, 256, 0, stream>>>(hA, row_ptr, adj, dis, W3, b3, hB, N, 0);

    // pool + final linear
    const int pool_blocks = 512;
    const int chunk = (N + pool_blocks - 1) / pool_blocks;
    pool_partial<<<pool_blocks, 256, 0, stream>>>(hB, batch, N, chunk, pooled);
    pool_linear<<<(G + 3) / 4, 256, 0, stream>>>(pooled, lin_w, lin_b, out, G);
}

// Round 11
// 279.336 us; speedup vs baseline: 1.5786x; 1.2898x over previous
//
#include <hip/hip_runtime.h>
#include <hip/hip_fp16.h>

#define D 64
#define NBMAX 512      // max buckets (nodes/256, N<=131072)
#define BCAP 5120      // per-bucket capacity
#define TILE 64        // nodes per block in tile_layer
#define ASTH 72        // LDS bf16 acc row stride in halves (144B: 16B-aligned, 2-way banks)
#define ACAP 448       // per-wave LDS adjacency buffer (entries)
// R10 lesson: fusing per-edge nodecnt atomics into bucket_scatter doubled its
// cost (43/65 -> 84us, WRITE 60MB) and the global-cursor build_scatter didn't
// pay for bucket_build's removal (total 360). Five rounds of fixed-region
// surgery: all neutral-to-worse -> the CSR build is latency-bound serial
// structure, not a traffic bug. tile_layer's 85MB FETCH is ~the COMPULSORY
// per-XCD footprint (8 XCDs x ~11MB each; capacity irrelevant, R7 proved
// row-splitting backfires) at ~2.5-3TB/s L3 random service -> within ~35% of
// floor. R11: restore the best-measured configuration exactly (R3/R6 = 277.6
// /278.2us): R0-form bucket_scatter, scan_buckets, bucket_build, R6 tile_layer.

typedef __attribute__((ext_vector_type(8))) short short8;
typedef __attribute__((ext_vector_type(4))) float float4v;

static __device__ __forceinline__ unsigned short f2bf(float x) {
    unsigned u = __float_as_uint(x);
    u += 0x7FFFu + ((u >> 16) & 1);   // RNE
    return (unsigned short)(u >> 16);
}

__global__ void zero_ints(int* __restrict__ p, int n) {
    int i = blockIdx.x * blockDim.x + threadIdx.x;
    if (i < n) p[i] = 0;
}

// x (fp32) -> xh (fp16), pre-scaled by dis[row]: s = dis[n]*x[n]
__global__ void prescale_x(const float* __restrict__ x, const float* __restrict__ dis,
                           __half* __restrict__ out, int n2) {
    int i = blockIdx.x * blockDim.x + threadIdx.x;
    if (i < n2) {
        int n = i >> 5;                 // 32 half2 per row
        float d = dis[n];
        float2 v = ((const float2*)x)[i];
        ((__half2*)out)[i] = __floats2half2_rn(v.x * d, v.y * d);
    }
}

// Bin edges into buckets of 256 consecutive dst nodes. Entry packed to 4B:
// (src << 8) | (dst & 255)   (src < 2^24).
__global__ __launch_bounds__(256) void bucket_scatter(const int* __restrict__ src,
                                                      const int* __restrict__ dst, int E,
                                                      int nb, int* __restrict__ gcursor,
                                                      unsigned* __restrict__ bpair) {
    __shared__ int lhist[NBMAX];
    __shared__ int lbase[NBMAX];
    int t = threadIdx.x;
    for (int i = t; i < nb; i += 256) lhist[i] = 0;
    __syncthreads();
    int e0 = blockIdx.x * 4096, e1 = min(e0 + 4096, E);
    for (int e = e0 + t; e < e1; e += 256) atomicAdd(&lhist[dst[e] >> 8], 1);
    __syncthreads();
    for (int i = t; i < nb; i += 256) {
        int c = lhist[i];
        lbase[i] = c ? atomicAdd(&gcursor[i], c) : 0;
        lhist[i] = 0;
    }
    __syncthreads();
    for (int e = e0 + t; e < e1; e += 256) {
        int d = dst[e];
        int b = d >> 8;
        int r = lbase[b] + atomicAdd(&lhist[b], 1);
        if (r < BCAP)
            bpair[(long)b * BCAP + r] = ((unsigned)src[e] << 8) | (unsigned)(d & 255);
    }
}

// Exclusive scan of nb (<512) bucket counts -> gbase, total at gbase[nb].
__global__ void scan_buckets(const int* __restrict__ gcursor, int B, int* __restrict__ gbase) {
    __shared__ int s[512];
    int t = threadIdx.x;
    s[t] = (t < B) ? gcursor[t] : 0;
    __syncthreads();
    for (int off = 1; off < 512; off <<= 1) {
        int v = (t >= off) ? s[t - off] : 0;
        __syncthreads();
        s[t] += v;
        __syncthreads();
    }
    if (t < B) gbase[t] = (t == 0) ? 0 : s[t - 1];
    if (t == 0) gbase[B] = s[511];
}

// One block per bucket: local histogram + scan in LDS, emit row_ptr/dis and
// adj entries packed as (src << 6) | (dst & 63)  (tile-local dst, TILE=64).
__global__ __launch_bounds__(256) void bucket_build(const unsigned* __restrict__ bpair,
                                                    int nb, int N,
                                                    const int* __restrict__ gcursor,
                                                    const int* __restrict__ gbase,
                                                    int* __restrict__ row_ptr,
                                                    float* __restrict__ dis,
                                                    int* __restrict__ adj) {
    __shared__ int hist[256];
    __shared__ int cur[256];
    __shared__ int wsum[4];
    int b = blockIdx.x, t = threadIdx.x;
    int cnt = gcursor[b];
    if (cnt > BCAP) cnt = BCAP;
    int ebase = gbase[b];
    const unsigned* bp = bpair + (long)b * BCAP;

    hist[t] = 0;
    __syncthreads();
    for (int i = t; i < cnt; i += 256) atomicAdd(&hist[bp[i] & 255u], 1);
    __syncthreads();
    int val = hist[t];
    int lane = t & 63, wv = t >> 6;
    int v = val;
#pragma unroll
    for (int off = 1; off < 64; off <<= 1) {
        int u = __shfl_up(v, off, 64);
        if (lane >= off) v += u;
    }
    if (lane == 63) wsum[wv] = v;
    __syncthreads();
    int wo = 0;
#pragma unroll
    for (int w = 0; w < 4; w++)
        if (w < wv) wo += wsum[w];
    int excl = wo + v - val;
    int node = (b << 8) + t;
    if (node < N) {
        row_ptr[node] = ebase + excl;
        dis[node] = rsqrtf((float)(val + 1));  // +1 self-loop
    }
    cur[t] = ebase + excl;
    __syncthreads();
    for (int i = t; i < cnt; i += 256) {
        unsigned p = bp[i];
        unsigned dl = p & 255u;
        int pos = atomicAdd(&cur[dl], 1);
        adj[pos] = (int)((p >> 8) << 6) | (int)(dl & 63u);
    }
    if (b == 0 && t == 0) row_ptr[N] = gbase[nb];
}

// Tile GCN layer on pre-scaled storage s[n] = dis[n]*h[n]:  (R6 body, proven)
//   y[n] = dis[n] * ( sum_a s[a] + s[n] );  o = relu(y @ W + b); store (*dis if scale_out)
// Block = 64-node tile, 4 waves x 16 rows. Lane = (row = lane>>2, c = lane&3).
// Contiguous-quad gather: lane c owns row bytes [c*16,+16) and [64+c*16,+16);
// each quad load = one fully-used 64B line. Per-lane fp32 register
// accumulation, no LDS atomics, no divergence. Epilogue: *dis, bf16 pack,
// two 16B LDS writes, wave-local waitcnt, per-wave MFMA.
template <int NB>
static __device__ __forceinline__ void tile_layer_body(const __half* __restrict__ in,
                                                       const int* __restrict__ row_ptr,
                                                       const int* __restrict__ adj,
                                                       const float* __restrict__ dis,
                                                       const float* __restrict__ Wg,
                                                       const float* __restrict__ bias,
                                                       __half* __restrict__ out,
                                                       int N, int scale_out) {
    __shared__ __align__(16) unsigned short accb[TILE * ASTH];  // 9216 B bf16 acc
    __shared__ int adjbuf[4][ACAP];                             // 7168 B wave-private

    int t = threadIdx.x;
    int lane = t & 63;
    int w = t >> 6;
    int row = lane >> 2;                    // wave-local row 0..15
    int c = lane & 3;                       // quad slot
    int col = lane & 15, quad = lane >> 4;  // epilogue MFMA coords

    int t0 = blockIdx.x * TILE;
    int wbase = t0 + w * 16;
    int node = wbase + row;

    // per-lane CSR range (empty for tail rows)
    int e0r = 0, e1r = 0;
    if (node < N) { e0r = row_ptr[node]; e1r = row_ptr[node + 1]; }

    const char* inb = (const char*)in;
    int* adjw = adjbuf[w];
    unsigned c16 = (unsigned)c * 16u;       // byte offset within each 64B half-row

    float a[16];                            // a[0..7]=ch[8c..8c+8), a[8..15]=ch[32+8c..)
#pragma unroll
    for (int j = 0; j < 16; j++) a[j] = 0.f;

#define ADD16(xa, ya)                                                   \
    {                                                                   \
        const __half2* h0 = (const __half2*)&(xa);                      \
        const __half2* h1 = (const __half2*)&(ya);                      \
        _Pragma("unroll")                                               \
        for (int j = 0; j < 4; j++) {                                   \
            float2 f = __half22float2(h0[j]);                           \
            a[2 * j] += f.x; a[2 * j + 1] += f.y;                       \
        }                                                               \
        _Pragma("unroll")                                               \
        for (int j = 0; j < 4; j++) {                                   \
            float2 f = __half22float2(h1[j]);                           \
            a[8 + 2 * j] += f.x; a[8 + 2 * j + 1] += f.y;               \
        }                                                               \
    }

    if (node < N) {
        unsigned rb = (unsigned)node * 128u + c16;
        int4 xa = *(const int4*)(inb + rb);
        int4 xb = *(const int4*)(inb + rb + 64);
        ADD16(xa, xb)
    }

    // ---- edge sweep: wave's contiguous CSR range, staged in ACAP chunks ----
    int wn0 = min(wbase, N);
    int wn1 = min(wbase + 16, N);
    int eb_w = row_ptr[wn0];
    int ee_w = row_ptr[wn1];

    for (int base = eb_w; base < ee_w; base += ACAP) {
        int clen = min(ACAP, ee_w - base);
        // cooperative wave-copy of adj slice (coalesced dwords); wave-private.
        for (int i = lane; i < clen; i += 64) adjw[i] = adj[base + i];
        __builtin_amdgcn_s_waitcnt(0);   // drain lds writes + vm before reads

        int ls = max(e0r - base, 0);
        int le = min(e1r - base, clen);
        int cnt = max(le - ls, 0);
        int kmax = cnt;
#pragma unroll
        for (int off = 32; off >= 1; off >>= 1) {
            int o = __shfl_xor(kmax, off, 64);
            kmax = max(kmax, o);
        }
        int sidx = min(ls, clen - 1);    // safe clamped index for short lanes

        for (int k = 0; k < kmax; k += NB) {
            bool ok[NB];
            unsigned ro[NB];
            int4 xa[NB], xb[NB];
#pragma unroll
            for (int u = 0; u < NB; u++) {
                int idx = ls + k + u;
                ok[u] = idx < le;
                int pk = adjw[ok[u] ? idx : sidx];
                ro[u] = (unsigned)(pk >> 6) * 128u + c16;
            }
#pragma unroll
            for (int u = 0; u < NB; u++) {
                xa[u] = *(const int4*)(inb + ro[u]);        // quad: one 64B line
                xb[u] = *(const int4*)(inb + ro[u] + 64);   // quad: one 64B line
            }
#pragma unroll
            for (int u = 0; u < NB; u++)
                if (ok[u]) ADD16(xa[u], xb[u])
        }
    }
#undef ADD16

    // scale by dis(own row), convert to bf16, two 16B LDS writes
    float dA = (node < N) ? dis[node] : 0.f;
    unsigned short* ab = &accb[(w * 16 + row) * ASTH];
    unsigned pk[8];
#pragma unroll
    for (int j = 0; j < 8; j++)
        pk[j] = (unsigned)f2bf(a[2 * j] * dA) | ((unsigned)f2bf(a[2 * j + 1] * dA) << 16);
    *(int4*)(ab + 8 * c) = make_int4((int)pk[0], (int)pk[1], (int)pk[2], (int)pk[3]);
    *(int4*)(ab + 32 + 8 * c) = make_int4((int)pk[4], (int)pk[5], (int)pk[6], (int)pk[7]);
    __builtin_amdgcn_s_waitcnt(0);   // wave-local: acc rows read only by this wave

    // ---- MFMA epilogue: per wave, rows w*16 .. w*16+15 ----
    // A frags: row m = col, k = 32s + quad*8 + j (bf16 direct from LDS)
    const unsigned short* arp = &accb[(w * 16 + col) * ASTH + quad * 8];
    short8 Af0 = *(const short8*)arp;
    short8 Af1 = *(const short8*)(arp + 32);

    float dnv[4];
#pragma unroll
    for (int r = 0; r < 4; r++) {
        int onode = t0 + w * 16 + quad * 4 + r;
        dnv[r] = (onode < N) ? (scale_out ? dis[onode] : 1.f) : 0.f;
    }

    // B frags per output quadrant cc: B[k=32s+quad*8+j][d=16cc+col]
#pragma unroll
    for (int cc = 0; cc < 4; cc++) {
        short8 B0, B1;
#pragma unroll
        for (int j = 0; j < 8; j++) {
            B0[j] = (short)f2bf(Wg[(quad * 8 + j) * D + 16 * cc + col]);
            B1[j] = (short)f2bf(Wg[(32 + quad * 8 + j) * D + 16 * cc + col]);
        }
        float4v z = {0.f, 0.f, 0.f, 0.f};
        float4v v = __builtin_amdgcn_mfma_f32_16x16x32_bf16(Af0, B0, z, 0, 0, 0);
        v = __builtin_amdgcn_mfma_f32_16x16x32_bf16(Af1, B1, v, 0, 0, 0);
        float bc = bias[16 * cc + col];
        // C layout: col = lane&15 (dim 16cc+col), row = quad*4 + r (node)
#pragma unroll
        for (int r = 0; r < 4; r++) {
            int onode = t0 + w * 16 + quad * 4 + r;
            if (onode < N) {
                float vv = fmaxf(v[r] + bc, 0.f) * dnv[r];
                out[(long)onode * D + 16 * cc + col] = __float2half(vv);
            }
        }
    }
}

// Single variant: batch-4 sweep, natural register allocation.
__global__ __launch_bounds__(256) void tile_layer(const __half* __restrict__ in,
                                                  const int* __restrict__ row_ptr,
                                                  const int* __restrict__ adj,
                                                  const float* __restrict__ dis,
                                                  const float* __restrict__ Wg,
                                                  const float* __restrict__ bias,
                                                  __half* __restrict__ out,
                                                  int N, int scale_out) {
    tile_layer_body<4>(in, row_ptr, adj, dis, Wg, bias, out, N, scale_out);
}

// Pool phase 1: grid-chunked over sorted nodes; per-wave run accumulation,
// one atomicAdd per (graph-run, lane) per wave.
__global__ __launch_bounds__(256) void pool_partial(const __half* __restrict__ h,
                                                    const int* __restrict__ batch, int N,
                                                    int chunk, float* __restrict__ pooled) {
    int lane = threadIdx.x & 63;
    int wv = threadIdx.x >> 6;
    int c0 = blockIdx.x * chunk;
    int c1 = min(c0 + chunk, N);
    int g_cur = -1;
    float acc = 0.f;
    for (int n = c0 + wv; n < c1; n += 4) {
        int g = batch[n];
        if (g != g_cur) {
            if (g_cur >= 0) atomicAdd(&pooled[g_cur * D + lane], acc);
            g_cur = g;
            acc = 0.f;
        }
        acc += __half2float(h[n * D + lane]);
    }
    if (g_cur >= 0) atomicAdd(&pooled[g_cur * D + lane], acc);
}

// Pool phase 2: one wave per graph, dot with lin_w.
__global__ void pool_linear(const float* __restrict__ pooled,
                            const float* __restrict__ lin_w,
                            const float* __restrict__ lin_b,
                            float* __restrict__ out, int G) {
    int lane = threadIdx.x & 63;
    int g = blockIdx.x * (blockDim.x >> 6) + (threadIdx.x >> 6);
    if (g >= G) return;
    float t = pooled[g * D + lane] * lin_w[lane];
#pragma unroll
    for (int off = 32; off >= 1; off >>= 1) t += __shfl_down(t, off, 64);
    if (lane == 0) out[g] = t + lin_b[0];
}

extern "C" void kernel_launch(void* const* d_in, const int* in_sizes, int n_in,
                              void* d_out, int out_size, void* d_ws, size_t ws_size,
                              hipStream_t stream) {
    const float* x      = (const float*)d_in[0];
    const int*   edges  = (const int*)d_in[1];
    const int*   batch  = (const int*)d_in[2];
    const float* W1     = (const float*)d_in[3];
    const float* b1     = (const float*)d_in[4];
    const float* W2     = (const float*)d_in[5];
    const float* b2     = (const float*)d_in[6];
    const float* W3     = (const float*)d_in[7];
    const float* b3     = (const float*)d_in[8];
    const float* lin_w  = (const float*)d_in[9];
    const float* lin_b  = (const float*)d_in[10];
    float* out = (float*)d_out;

    const int N = in_sizes[2];        // 100000
    const int E = in_sizes[1] / 2;    // 1600000
    const int G = out_size;           // 64 graphs
    const int nb = (N + 255) >> 8;    // 391 buckets of 256 nodes

    const int* e_src = edges;         // edge_index[0]
    const int* e_dst = edges + E;     // edge_index[1]

    // workspace layout (4B-element offsets, 64-elem aligned)
    auto al = [](long v) { return (v + 63) & ~63L; };
    long o_gcur   = 0;                       // NBMAX ints
    long o_pooled = al(o_gcur + NBMAX);      // G*D floats
    long o_gbase  = al(o_pooled + (long)G * D);
    long o_rowptr = al(o_gbase + nb + 1);
    long o_dis    = al(o_rowptr + N + 1);
    long o_adjs   = al(o_dis + N);
    long o_xh     = al(o_adjs + E);              // N*D halves
    long o_hA     = al(o_xh + (long)N * D / 2);  // aliases bpair (8MB < 25.6MB slot)
    long o_hB     = o_hA + (long)N * D;          // fp32-sized slots used as half buffers

    int*    gcursor = (int*)d_ws + o_gcur;
    float*  pooled  = (float*)d_ws + o_pooled;
    int*    gbase   = (int*)d_ws + o_gbase;
    int*    row_ptr = (int*)d_ws + o_rowptr;
    float*  dis     = (float*)d_ws + o_dis;
    int*    adj     = (int*)d_ws + o_adjs;
    __half* xh      = (__half*)((float*)d_ws + o_xh);
    __half* hA      = (__half*)((float*)d_ws + o_hA);
    __half* hB      = (__half*)((float*)d_ws + o_hB);
    // bpair (nb*BCAP uints = 8 MB) aliases hA slot: dead before layer 2 writes hA.
    unsigned* bpair = (unsigned*)hA;

    // zero gcursor + pooled (contiguous)
    int nz = (int)(o_pooled + (long)G * D);
    zero_ints<<<(nz + 255) / 256, 256, 0, stream>>>((int*)d_ws, nz);

    // CSR build first (produces dis), then pre-scaled fp16 convert of x
    bucket_scatter<<<(E + 4095) / 4096, 256, 0, stream>>>(e_src, e_dst, E, nb, gcursor, bpair);
    scan_buckets<<<1, 512, 0, stream>>>(gcursor, nb, gbase);
    bucket_build<<<nb, 256, 0, stream>>>(bpair, nb, N, gcursor, gbase, row_ptr, dis, adj);

    int n2 = N * D / 2;
    prescale_x<<<(n2 + 255) / 256, 256, 0, stream>>>(x, dis, xh, n2);

    // fused GCN layers: xh -> hB -> hA -> hB
    // layers 1,2 store dis-pre-scaled output; layer 3 stores plain relu for pooling
    const int tl_blocks = (N + TILE - 1) / TILE;
    tile_layer<<<tl_blocks, 256, 0, stream>>>(xh, row_ptr, adj, dis, W1, b1, hB, N, 1);
    tile_layer<<<tl_blocks, 256, 0, stream>>>(hB, row_ptr, adj, dis, W2, b2, hA, N, 1);
    tile_layer<<<tl_blocks, 256, 0, stream>>>(hA, row_ptr, adj, dis, W3, b3, hB, N, 0);

    // pool + final linear
    const int pool_blocks = 512;
    const int chunk = (N + pool_blocks - 1) / pool_blocks;
    pool_partial<<<pool_blocks, 256, 0, stream>>>(hB, batch, N, chunk, pooled);
    pool_linear<<<(G + 3) / 4, 256, 0, stream>>>(pooled, lin_w, lin_b, out, G);
}